// Round 4
// baseline (48.611 us; speedup 1.0000x reference)
//
#include <hip/hip_runtime.h>

#define B_ 256
#define T_ 168
#define C_ 1024
#define H_ 24
#define TH 84   // half of T: t-split factor 2

// d_ws layout (floats): W[t*24 + k] for t in [0,168), k in [0,24); beta[k] at [168*24 + k]
// Total: 168*24 + 24 = 4056 floats = 16,224 bytes.

// One block. Thread t < 168 computes the whole column W[.][t] locally
// (W[k][t] depends only on W[j][t] for j<k -- same t, no cross-thread deps).
// Thread 168 computes beta.
__global__ __launch_bounds__(192) void ar_precompute(const float* __restrict__ w,
                                                     const float* __restrict__ bias,
                                                     float* __restrict__ ws) {
    __shared__ float lw[T_];
    const int t = threadIdx.x;
    if (t < T_) lw[t] = w[t];
    __syncthreads();
    if (t < T_) {
        float col[H_];
        #pragma unroll
        for (int k = 0; k < H_; ++k) {
            float v = (t >= k) ? lw[t - k] : 0.0f;
            #pragma unroll
            for (int j = 0; j < k; ++j)
                v += lw[T_ - k + j] * col[j];
            col[k] = v;
        }
        #pragma unroll
        for (int k = 0; k < H_; ++k)
            ws[t * H_ + k] = col[k];
    } else if (t == T_) {
        float bv = bias[0];
        float beta[H_];
        #pragma unroll
        for (int k = 0; k < H_; ++k) {
            float v = bv;
            #pragma unroll
            for (int j = 0; j < k; ++j)
                v += lw[T_ - k + j] * beta[j];
            beta[k] = v;
        }
        #pragma unroll
        for (int k = 0; k < H_; ++k)
            ws[T_ * H_ + k] = beta[k];
    }
}

// out[b,k,c] = beta[k] + sum_t W[k][t] * y[b,t,c]
// t-split for TLP: block = 256 threads = 128 c-columns x 2 t-halves.
// Grid = (C/128, B) = 2048 blocks -> 8 blocks/CU -> 32 waves/CU (occupancy cap).
// Round-4 deltas: #pragma unroll 7 (84=7x12) -> 7 loads in flight per wave
// (56 KB/CU vs 32 KB at unroll 4; BW-latency product is ~22 KB/CU), and
// nontemporal y loads / out stores (pure stream, no reuse -> nt flag).
// h=1 deposits partials in LDS ([24][128] transposed: stride-4B across lanes,
// conflict-free); h=0 reduces, adds beta, stores.
__global__ __launch_bounds__(256, 8) void ar_main(const float* __restrict__ y,
                                                  const float* __restrict__ ws,
                                                  float* __restrict__ out) {
    __shared__ float sacc[H_ * 128];

    const int tid = threadIdx.x;
    const int c_local = tid & 127;
    // tid>>7 is uniform across each wave (lanes 0-63 share it); force scalar so
    // W addresses stay provably uniform -> s_load_dwordx4 on the scalar pipe.
    const int h = __builtin_amdgcn_readfirstlane(tid >> 7);

    const int c = blockIdx.x * 128 + c_local;
    const int b = blockIdx.y;
    const float* __restrict__ yp =
        y + (size_t)b * (size_t)(T_ * C_) + (size_t)(h * TH) * C_ + c;

    float acc[H_];
    #pragma unroll
    for (int k = 0; k < H_; ++k) acc[k] = 0.0f;

    #pragma unroll 7
    for (int tt = 0; tt < TH; ++tt) {
        const float yv = __builtin_nontemporal_load(yp + (size_t)tt * C_);
        const float4* __restrict__ w4 = (const float4*)(ws + (h * TH + tt) * H_);
        #pragma unroll
        for (int q = 0; q < H_ / 4; ++q) {             // uniform addr -> s_load_dwordx4
            const float4 wv = w4[q];
            acc[4 * q + 0] += wv.x * yv;
            acc[4 * q + 1] += wv.y * yv;
            acc[4 * q + 2] += wv.z * yv;
            acc[4 * q + 3] += wv.w * yv;
        }
    }

    if (h == 1) {
        #pragma unroll
        for (int k = 0; k < H_; ++k)
            sacc[k * 128 + c_local] = acc[k];          // conflict-free (4B stride)
    }
    __syncthreads();
    if (h == 0) {
        const float* __restrict__ beta = ws + T_ * H_; // uniform -> s_load
        float* __restrict__ op = out + ((size_t)b * H_) * C_ + c;
        #pragma unroll
        for (int k = 0; k < H_; ++k)
            __builtin_nontemporal_store(acc[k] + sacc[k * 128 + c_local] + beta[k],
                                        op + (size_t)k * C_);
    }
}

extern "C" void kernel_launch(void* const* d_in, const int* in_sizes, int n_in,
                              void* d_out, int out_size, void* d_ws, size_t ws_size,
                              hipStream_t stream) {
    // inputs: 0=x (unused), 1=y (B,T,C), 2=w (1,168), 3=b (1,)
    const float* y    = (const float*)d_in[1];
    const float* w    = (const float*)d_in[2];
    const float* bias = (const float*)d_in[3];
    float* out = (float*)d_out;
    float* ws  = (float*)d_ws;

    ar_precompute<<<1, 192, 0, stream>>>(w, bias, ws);
    ar_main<<<dim3(C_ / 128, B_), 256, 0, stream>>>(y, ws, out);
}

// Round 5
// 45.704 us; speedup vs baseline: 1.0636x; 1.0636x over previous
//
#include <hip/hip_runtime.h>

#define B_ 256
#define T_ 168
#define C_ 1024
#define H_ 24
#define TH 84   // half of T: t-split factor 2
#define WW 28   // rotating w-window: >= H_, divides TH (84 = 3*28)

// Fully fused single kernel, zero precompute dispatch.
//
// Math: pred_k = sum_{n=0}^{167-k} w[n] y[n+k]  + sum_{j<k} w[168-k+j] pred_j + b
//   (substitute t=n+k):  S_k = sum_{t=k}^{167} w[t-k] y[b,t,c]
//   pred_k = S_k + b + sum_{j<k} w[168-k+j] pred_j      (276-FMA epilogue)
//
// Hot loop computes S_k with taps from a 28-slot rotating window of raw w
// values. All window indices are compile-time constants (inner 28-body fully
// unrolled; 28 | 84 so slot == j). w addresses are uniform -> s_load -> SGPR;
// FMAs are v_fmac v, s, v. One s_load per t (round-3 had six s_load_dwordx4).
// Zero-init window gives w[t-k<0] = 0 (the t>=k triangle) for free.
//
// t-split for TLP (round-3 win, +8%): block = 256 threads = 128 c x 2 t-halves.
// Grid = (C/128, B) = 2048 blocks -> 8 blocks/CU -> 32 waves/CU (cap).
// h=1 deposits partials in LDS ([24][128]: stride-4B across lanes, conflict-
// free); h=0 reduces, runs the recurrence epilogue, stores.
__global__ __launch_bounds__(256, 8) void ar_fused(const float* __restrict__ y,
                                                   const float* __restrict__ w,
                                                   const float* __restrict__ bias,
                                                   float* __restrict__ out) {
    __shared__ float sacc[H_ * 128];

    const int tid = threadIdx.x;
    const int c_local = tid & 127;
    // tid>>7 is wave-uniform; force scalar so w addresses stay provably uniform.
    const int h = __builtin_amdgcn_readfirstlane(tid >> 7);

    const int c = blockIdx.x * 128 + c_local;
    const int b = blockIdx.y;
    const float* __restrict__ yp =
        y + (size_t)b * (size_t)(T_ * C_) + (size_t)(h * TH) * C_ + c;

    float acc[H_];
    #pragma unroll
    for (int k = 0; k < H_; ++k) acc[k] = 0.0f;

    // Rotating window: at step t, win[(t % WW)] <- w[t]; tap for acc[k] is
    // win[(t-k) % WW]. Zero-init => taps for t-k < 0 read 0.
    float win[WW];
    #pragma unroll
    for (int s = 0; s < WW; ++s) win[s] = 0.0f;
    if (h == 1) {
        // preload w[TH-23 .. TH-1] into slots (TH-d) % WW == WW-d  (TH%WW==0)
        #pragma unroll
        for (int d = 1; d <= H_ - 1; ++d) win[WW - d] = w[TH - d];
    }

    for (int tb = 0; tb < TH / WW; ++tb) {
        #pragma unroll
        for (int j = 0; j < WW; ++j) {
            win[j] = w[h * TH + tb * WW + j];          // uniform -> s_load
            const float yv = yp[(size_t)(tb * WW + j) * C_];  // coalesced
            #pragma unroll
            for (int k = 0; k < H_; ++k)
                acc[k] += win[(j - k + WW) % WW] * yv; // static index, SGPR tap
        }
    }

    if (h == 1) {
        #pragma unroll
        for (int k = 0; k < H_; ++k)
            sacc[k * 128 + c_local] = acc[k];          // conflict-free (4B stride)
    }
    __syncthreads();
    if (h == 0) {
        // AR recurrence epilogue: taps w[145..167], all uniform scalars.
        float wtail[H_ - 1];
        #pragma unroll
        for (int i = 0; i < H_ - 1; ++i) wtail[i] = w[T_ - (H_ - 1) + i];
        const float bv = bias[0];                      // uniform -> s_load
        float pred[H_];
        float* __restrict__ op = out + ((size_t)b * H_) * C_ + c;
        #pragma unroll
        for (int k = 0; k < H_; ++k) {
            float v = acc[k] + sacc[k * 128 + c_local] + bv;
            #pragma unroll
            for (int j = 0; j < k; ++j)
                v += wtail[H_ - 1 - k + j] * pred[j];  // w[168-k+j] * pred_j
            pred[k] = v;
            op[(size_t)k * C_] = v;                    // coalesced across lanes
        }
    }
}

extern "C" void kernel_launch(void* const* d_in, const int* in_sizes, int n_in,
                              void* d_out, int out_size, void* d_ws, size_t ws_size,
                              hipStream_t stream) {
    // inputs: 0=x (unused), 1=y (B,T,C), 2=w (1,168), 3=b (1,)
    const float* y    = (const float*)d_in[1];
    const float* w    = (const float*)d_in[2];
    const float* bias = (const float*)d_in[3];
    float* out = (float*)d_out;

    ar_fused<<<dim3(C_ / 128, B_), 256, 0, stream>>>(y, w, bias, out);
}

// Round 6
// 39.942 us; speedup vs baseline: 1.2170x; 1.1442x over previous
//
#include <hip/hip_runtime.h>

#define B_ 256
#define T_ 168
#define C_ 1024
#define H_ 24
#define TH 84   // half of T: t-split factor 2

// d_ws layout (floats): W[t*24 + k] for t in [0,168), k in [0,24); beta[k] at [168*24 + k]
// Total: 168*24 + 24 = 4056 floats = 16,224 bytes.

// One block. Thread t < 168 computes the whole column W[.][t] locally
// (W[k][t] depends only on W[j][t] for j<k -- same t, no cross-thread deps).
// Thread 168 computes beta.
__global__ __launch_bounds__(192) void ar_precompute(const float* __restrict__ w,
                                                     const float* __restrict__ bias,
                                                     float* __restrict__ ws) {
    __shared__ float lw[T_];
    const int t = threadIdx.x;
    if (t < T_) lw[t] = w[t];
    __syncthreads();
    if (t < T_) {
        float col[H_];
        #pragma unroll
        for (int k = 0; k < H_; ++k) {
            float v = (t >= k) ? lw[t - k] : 0.0f;
            #pragma unroll
            for (int j = 0; j < k; ++j)
                v += lw[T_ - k + j] * col[j];
            col[k] = v;
        }
        #pragma unroll
        for (int k = 0; k < H_; ++k)
            ws[t * H_ + k] = col[k];
    } else if (t == T_) {
        float bv = bias[0];
        float beta[H_];
        #pragma unroll
        for (int k = 0; k < H_; ++k) {
            float v = bv;
            #pragma unroll
            for (int j = 0; j < k; ++j)
                v += lw[T_ - k + j] * beta[j];
            beta[k] = v;
        }
        #pragma unroll
        for (int k = 0; k < H_; ++k)
            ws[T_ * H_ + k] = beta[k];
    }
}

// out[b,k,c] = beta[k] + sum_t W[k][t] * y[b,t,c]
// t-split for TLP: block = 256 threads = 128 c-columns x 2 t-halves.
// Grid = (C/128, B) = 2048 blocks -> 8 blocks/CU -> 32 waves/CU (occupancy cap).
// Round-6 single delta vs round-3: #pragma unroll 6 (84 = 6x14) -> ~4.5 loads
// in flight per wave avg (~36 KB/CU vs ~20 KB at unroll 4; BW-latency product
// is ~22 KB/CU at ~900 ns HBM-miss latency). NO nontemporal (R4 confound).
// h=1 deposits partials in LDS ([24][128] transposed: stride-4B across lanes,
// conflict-free); h=0 reduces, adds beta, stores.
__global__ __launch_bounds__(256, 8) void ar_main(const float* __restrict__ y,
                                                  const float* __restrict__ ws,
                                                  float* __restrict__ out) {
    __shared__ float sacc[H_ * 128];

    const int tid = threadIdx.x;
    const int c_local = tid & 127;
    // tid>>7 is uniform across each wave (lanes 0-63 share it); force scalar so
    // W addresses stay provably uniform -> s_load_dwordx4 on the scalar pipe.
    const int h = __builtin_amdgcn_readfirstlane(tid >> 7);

    const int c = blockIdx.x * 128 + c_local;
    const int b = blockIdx.y;
    const float* __restrict__ yp =
        y + (size_t)b * (size_t)(T_ * C_) + (size_t)(h * TH) * C_ + c;

    float acc[H_];
    #pragma unroll
    for (int k = 0; k < H_; ++k) acc[k] = 0.0f;

    #pragma unroll 6
    for (int tt = 0; tt < TH; ++tt) {
        const float yv = yp[(size_t)tt * C_];          // coalesced across lanes
        const float4* __restrict__ w4 = (const float4*)(ws + (h * TH + tt) * H_);
        #pragma unroll
        for (int q = 0; q < H_ / 4; ++q) {             // uniform addr -> s_load_dwordx4
            const float4 wv = w4[q];
            acc[4 * q + 0] += wv.x * yv;
            acc[4 * q + 1] += wv.y * yv;
            acc[4 * q + 2] += wv.z * yv;
            acc[4 * q + 3] += wv.w * yv;
        }
    }

    if (h == 1) {
        #pragma unroll
        for (int k = 0; k < H_; ++k)
            sacc[k * 128 + c_local] = acc[k];          // conflict-free (4B stride)
    }
    __syncthreads();
    if (h == 0) {
        const float* __restrict__ beta = ws + T_ * H_; // uniform -> s_load
        float* __restrict__ op = out + ((size_t)b * H_) * C_ + c;
        #pragma unroll
        for (int k = 0; k < H_; ++k)
            op[(size_t)k * C_] = acc[k] + sacc[k * 128 + c_local] + beta[k];
    }
}

extern "C" void kernel_launch(void* const* d_in, const int* in_sizes, int n_in,
                              void* d_out, int out_size, void* d_ws, size_t ws_size,
                              hipStream_t stream) {
    // inputs: 0=x (unused), 1=y (B,T,C), 2=w (1,168), 3=b (1,)
    const float* y    = (const float*)d_in[1];
    const float* w    = (const float*)d_in[2];
    const float* bias = (const float*)d_in[3];
    float* out = (float*)d_out;
    float* ws  = (float*)d_ws;

    ar_precompute<<<1, 192, 0, stream>>>(w, bias, ws);
    ar_main<<<dim3(C_ / 128, B_), 256, 0, stream>>>(y, ws, out);
}